// Round 9
// baseline (102.776 us; speedup 1.0000x reference)
//
#include <hip/hip_runtime.h>
#include <hip/hip_bf16.h>

typedef unsigned short u16;
typedef __attribute__((ext_vector_type(8))) short short8;
typedef __attribute__((ext_vector_type(4))) float floatx4;

#define NROWS 8192
#define DIM 256

__device__ __forceinline__ void atomicMinFloat(float* addr, float val) {
    if (val >= 0.0f) {
        atomicMin((int*)addr, __float_as_int(val));
    } else {
        atomicMax((unsigned int*)addr, __float_as_uint(val));
    }
}

__device__ __forceinline__ u16 f32_to_bf16_rne(float x) {
    unsigned int u = __float_as_uint(x);
    unsigned int r = (u + 0x7fffu + ((u >> 16) & 1u)) >> 16;
    return (u16)r;
}

// C(M) = -logp * exp(logp); quasiconcave in M => rowmin = min(C(minM), C(maxM)).
__device__ __forceinline__ float c_of_m(float m) {
    const float INV_SIG = 1.0f / 0.3f;
    const float KC = 0.28503427f;  // -ln(0.3) - 0.5*ln(2*pi)
    float z = (m - 1.0f) * INV_SIG;
    float logp = fmaf(-0.5f * z, z, KC);
    return -logp * __expf(logp);
}

// 16B async DMA global -> LDS. LDS dest is wave-uniform base + lane*16.
__device__ __forceinline__ void load16(const u16* g, u16* l) {
    __builtin_amdgcn_global_load_lds(
        (__attribute__((address_space(1))) void*)g,
        (__attribute__((address_space(3))) void*)l, 16, 0, 0);
}

// Normalize rows (L2-norm clamped at 1e-8), wave per row, float4 loads.
// BOTH X and Y are written in MFMA fragment ("panel") layout:
//   element (row r, k) -> flat[ ((p*8+kt)*64 + lq*16 + lm)*8 + j ]
//   p=r>>4, lm=r&15, kt=k>>5, lq=(k>>3)&3, j=k&7.
// A fragment load is then base + lane*16B: one coalesced dwordx4.
// Verified end-to-end R5/R11/R14/R15 (absmax 1.5e-5).
__global__ __launch_bounds__(256) void normalize_kernel(const float* __restrict__ Ex,
                                                        const float* __restrict__ Ey,
                                                        u16* __restrict__ Xs,
                                                        u16* __restrict__ Ys,
                                                        float* __restrict__ out) {
    const int t = threadIdx.x;
    const int ln = t & 63;
    const int row = blockIdx.x * 4 + (t >> 6);
    const float* src = (blockIdx.y == 0) ? Ex : Ey;
    u16* dst = (blockIdx.y == 0) ? Xs : Ys;

    float4 v = *(const float4*)(src + (size_t)row * DIM + ln * 4);
    float s = fmaf(v.x, v.x, fmaf(v.y, v.y, fmaf(v.z, v.z, v.w * v.w)));
    #pragma unroll
    for (int m = 32; m >= 1; m >>= 1) s += __shfl_xor(s, m, 64);
    float inv = 1.0f / fmaxf(sqrtf(s), 1e-8f);

    ushort4 o;
    o.x = f32_to_bf16_rne(v.x * inv);
    o.y = f32_to_bf16_rne(v.y * inv);
    o.z = f32_to_bf16_rne(v.z * inv);
    o.w = f32_to_bf16_rne(v.w * inv);

    const int p = row >> 4;
    const int lm = row & 15;
    const int kt = ln >> 3;
    const int lq = (ln >> 1) & 3;
    const int j4 = (ln & 1) * 4;
    const size_t off = ((size_t)((p * 8 + kt) * 64 + lq * 16 + lm)) * 8 + j4;
    *(ushort4*)(dst + off) = o;

    if (blockIdx.y == 0 && ln == 0) out[row] = __uint_as_float(0x7f800000u);  // +inf
}

// R25: self-staged cross-barrier prefetch + rotated kt order.
// R7/R8 established: untouchable harness overhead ~58 us; gemm ~30 us at
// MfmaUtil 49%, 2 waves/SIMD (VGPR box closed). Remaining measured gap =
// ct-start bubble: post-__syncthreads all waves burst ds_reads and stall
// ~200+ cyc while the MFMA pipe idles. Fix:
//  (1) stage map: wave w DMA-stages exactly units (kt=w, cg0/cg1) -- the
//      fragments IT consumes first.
//  (2) rotated compute order: wave w processes kt=(w+s)&7, s=0..7. A-frags
//      are re-indexed at LOAD time (a[rg][s] holds kt=(w+s)&7) so all
//      register indices stay compile-time static (rule #20).
//  (3) at the END of ct k: s_waitcnt vmcnt(0) (own DMAs, issued ~2000 cyc
//      earlier -- free), then ds_read own s=0 frags of buf^1 BEFORE the
//      barrier. Legal: the wave staged those bytes itself. Post-barrier the
//      first MFMA cluster starts from registers immediately.
// Per-(row,col) K-order is rotated (fp32 reassoc only). 2-deep bfA/bfB
// pipeline and early-fold retained from R7/R8.
// Grid 256 (1 block/CU); XCD swizzle keeps A+B in the local L2.
__global__ void __launch_bounds__(512, 2)
gemm_min_kernel(const u16* __restrict__ Xs,
                const u16* __restrict__ Ys,
                float* __restrict__ out) {
    __shared__ u16 Bs[2][16 * 512];  // 2 x 16 KB

    const int tid = threadIdx.x;
    const int w = tid >> 6;      // 0..7 row-group (64 rows each)
    const int lane = tid & 63;
    const int lq = lane >> 4;
    const int lm = lane & 15;

    // XCD-aware remap (dispatch i -> XCD i&7 round-robin): XCD x gets a
    // 4 row-tile x 8 col-group region. Bijective over the 16x16 grid.
    const int i = blockIdx.x;
    const int x = i & 7;
    const int jj = i >> 3;                      // 0..31 within XCD
    const int rt = (x & 3) * 4 + (jj & 3);      // row-tile 0..15
    const int cgrp = (x >> 2) * 8 + (jj >> 2);  // col-group 0..15

    const int rowStart = rt * 512;
    const int rowPan0 = rt * 32 + w * 4;
    const u16* ybase = Ys + (size_t)cgrp * 32 * 4096;  // advances 8192 u16/ct

    // Wave w stages its OWN first-needed fragments of the 32col x 256k tile:
    // unit (kt=w, cg) -> global (cg*4096 + w*512), LDS slot (cg*8 + w)*512.
    // Exclusive map (8 waves x 2 units = 16 units).
    auto stageOwn = [&](int buf, const u16* yb) {
        load16(yb + 0 * 4096 + w * 512 + lane * 8, &Bs[buf][(0 * 8 + w) * 512]);
        load16(yb + 1 * 4096 + w * 512 + lane * 8, &Bs[buf][(8 + w) * 512]);
    };

    // a[rg][s] holds the A-frag for kt=(w+s)&7: rotation resolved at load
    // time so compute-side register indices are static.
    short8 a[4][8];
    auto loadA = [&](int s) {
        const int kt = (w + s) & 7;
        #pragma unroll
        for (int rg = 0; rg < 4; ++rg)
            a[rg][s] = *(const short8*)(
                Xs + ((size_t)(rowPan0 + rg) * 8 + kt) * 512 + lane * 8);
    };

    floatx4 mn4[4], mx4[4];
    #pragma unroll
    for (int rg = 0; rg < 4; ++rg) {
        mn4[rg] = (floatx4){3.4e38f, 3.4e38f, 3.4e38f, 3.4e38f};
        mx4[rg] = (floatx4){-3.4e38f, -3.4e38f, -3.4e38f, -3.4e38f};
    }

    floatx4 acc[4][2];
    const floatx4 FZ = (floatx4){0.0f, 0.0f, 0.0f, 0.0f};
    short8 bfA[2], bfB[2];  // persist across the barrier (prefetched s=0)

    auto fold = [&]() {
        #pragma unroll
        for (int rg = 0; rg < 4; ++rg)
            #pragma unroll
            for (int cg = 0; cg < 2; ++cg)
                #pragma unroll
                for (int r = 0; r < 4; ++r) {
                    float m = acc[rg][cg][r];
                    mn4[rg][r] = fminf(mn4[rg][r], m);
                    mx4[rg][r] = fmaxf(mx4[rg][r], m);
                }
    };

    // compute: 2-deep bfA/bfB pipeline over rotated kt order. PRE: s=0 frags
    // already in bfA (cross-barrier prefetch). dofold: fold prev ct's acc in
    // the s=1 read-latency window. doPrefetch: at the end, vmcnt-drain own
    // DMAs and read own s=0 frags of buf^1 for the next ct.
    auto compute = [&](int buf, bool PRE, bool dofold, bool doPrefetch) {
        const u16* bsb = &Bs[buf][0];
        auto rdB = [&](short8* dst, int s) {
            const int kt = (w + s) & 7;
            dst[0] = *(const short8*)(bsb + (0 * 8 + kt) * 512 + lane * 8);
            dst[1] = *(const short8*)(bsb + (8 + kt) * 512 + lane * 8);
        };
        if (!PRE) rdB(bfA, 0);
        rdB(bfB, 1);
        if (dofold) fold();
        #pragma unroll
        for (int s2 = 0; s2 < 4; ++s2) {
            const int se = 2 * s2;      // even slot, uses bfA, A = a[rg][se]
            const int so = se + 1;      // odd slot, uses bfB
            if (se == 0) {
                #pragma unroll
                for (int cg = 0; cg < 2; ++cg)
                    #pragma unroll
                    for (int rg = 0; rg < 4; ++rg)
                        acc[rg][cg] = __builtin_amdgcn_mfma_f32_16x16x32_bf16(
                            a[rg][0], bfA[cg], FZ, 0, 0, 0);
            } else {
                #pragma unroll
                for (int cg = 0; cg < 2; ++cg)
                    #pragma unroll
                    for (int rg = 0; rg < 4; ++rg)
                        acc[rg][cg] = __builtin_amdgcn_mfma_f32_16x16x32_bf16(
                            a[rg][se], bfA[cg], acc[rg][cg], 0, 0, 0);
            }
            if (se + 2 < 8) rdB(bfA, se + 2);
            #pragma unroll
            for (int cg = 0; cg < 2; ++cg)
                #pragma unroll
                for (int rg = 0; rg < 4; ++rg)
                    acc[rg][cg] = __builtin_amdgcn_mfma_f32_16x16x32_bf16(
                        a[rg][so], bfB[cg], acc[rg][cg], 0, 0, 0);
            if (so + 2 < 8) rdB(bfB, so + 2);
        }
        if (doPrefetch) {
            // Own DMAs for buf^1 were issued at this ct's start; drain them
            // (free) and pull own s=0 frags across the upcoming barrier.
            asm volatile("s_waitcnt vmcnt(0)" ::: "memory");
            const u16* bnb = &Bs[buf ^ 1][0];
            bfA[0] = *(const short8*)(bnb + (0 * 8 + w) * 512 + lane * 8);
            bfA[1] = *(const short8*)(bnb + (8 + w) * 512 + lane * 8);
        }
    };

    // --- ct = 0, peeled: overlap A prologue with B0 DMA ---
    stageOwn(0, ybase);
    loadA(0); loadA(1);
    __syncthreads();         // drains B0 DMA (+ the early A loads)
    stageOwn(1, ybase + 8192);  // prefetch ct=1's tile
    loadA(2); loadA(3); loadA(4); loadA(5); loadA(6); loadA(7);
    compute(0, false, false, true);
    ybase += 8192;

    // --- cts 1..15: steady state ---
    #pragma unroll 1
    for (int ct = 1; ct < 16; ++ct) {
        const int buf = ct & 1;
        __syncthreads();           // all DMAs for buf visible block-wide
        if (ct < 15)
            stageOwn(buf ^ 1, ybase + 8192);
        compute(buf, true, true, ct < 15);
        ybase += 8192;  // loop-carried: blocks cross-ct hoisting
    }
    fold();  // final ct's acc

    // Single epilogue: quad-lane reduce, eval C twice (quasiconcavity),
    // fire-and-forget atomicMin (no read guard -- R3 post-mortem).
    #pragma unroll
    for (int rg = 0; rg < 4; ++rg) {
        #pragma unroll
        for (int r = 0; r < 4; ++r) {
            float mn = mn4[rg][r];
            float mx = mx4[rg][r];
            #pragma unroll
            for (int mofs = 1; mofs < 16; mofs <<= 1) {
                mn = fminf(mn, __shfl_xor(mn, mofs, 64));
                mx = fmaxf(mx, __shfl_xor(mx, mofs, 64));
            }
            if (lm == 0) {
                float cmin = fminf(c_of_m(mn), c_of_m(mx));
                int row = rowStart + w * 64 + rg * 16 + lq * 4 + r;
                atomicMinFloat(&out[row], cmin);
            }
        }
    }
}

extern "C" void kernel_launch(void* const* d_in, const int* in_sizes, int n_in,
                              void* d_out, int out_size, void* d_ws, size_t ws_size,
                              hipStream_t stream) {
    const float* Ex = (const float*)d_in[0];
    const float* Ey = (const float*)d_in[1];
    float* out = (float*)d_out;
    u16* Xs = (u16*)d_ws;                // 4 MB, panel layout
    u16* Ys = Xs + (size_t)NROWS * DIM;  // 4 MB, panel layout

    hipLaunchKernelGGL(normalize_kernel, dim3(NROWS / 4, 2), dim3(256), 0, stream,
                       Ex, Ey, Xs, Ys, out);
    hipLaunchKernelGGL(gemm_min_kernel, dim3(16 * 16), dim3(512), 0, stream,
                       Xs, Ys, out);
}